// Round 6
// baseline (288.537 us; speedup 1.0000x reference)
//
#include <hip/hip_runtime.h>
#include <stdint.h>
#include <math.h>

// B=2 S=2048 E=1024 H=16 DH=64 ROT=32 CTX=2048
// d_in / d_out are FLOAT32 (per reference). Internals use bf16 MFMA.
typedef __bf16 bf16x8 __attribute__((ext_vector_type(8)));
typedef float f32x4 __attribute__((ext_vector_type(4)));

__device__ __forceinline__ float bf2f(uint16_t x) {
  unsigned u = ((unsigned)x) << 16;
  float f;
  __builtin_memcpy(&f, &u, 4);
  return f;
}
// native RTNE f32->bf16
__device__ __forceinline__ uint16_t f2bf(float f) {
  __bf16 h = (__bf16)f;
  uint16_t u;
  __builtin_memcpy(&u, &h, 2);
  return u;
}
// round two float4s to bf16x8
__device__ __forceinline__ bf16x8 pack8(float4 lo, float4 hi) {
  bf16x8 v;
  v[0] = (__bf16)lo.x; v[1] = (__bf16)lo.y; v[2] = (__bf16)lo.z; v[3] = (__bf16)lo.w;
  v[4] = (__bf16)hi.x; v[5] = (__bf16)hi.y; v[6] = (__bf16)hi.z; v[7] = (__bf16)hi.w;
  return v;
}
// load 8 contiguous f32, round to bf16x8
__device__ __forceinline__ bf16x8 cvt8(const float* p) {
  return pack8(*(const float4*)p, *(const float4*)(p + 4));
}

// direct global->LDS, 16B/lane; LDS dest = wave-uniform base + lane*16
typedef __attribute__((address_space(1))) const unsigned int gu32;
typedef __attribute__((address_space(3))) unsigned int lu32;
__device__ __forceinline__ void async_copy16(const void* gp, void* lp) {
  __builtin_amdgcn_global_load_lds((gu32*)gp, (lu32*)lp, 16, 0, 0);
}

// f32 -> bf16 elementwise convert; grid.z selects tensor, grid.x*256*8 = count
__global__ __launch_bounds__(256) void cvt_kernel(
    const float* __restrict__ s0, uint16_t* __restrict__ d0,
    const float* __restrict__ s1, uint16_t* __restrict__ d1,
    const float* __restrict__ s2, uint16_t* __restrict__ d2,
    const float* __restrict__ s3, uint16_t* __restrict__ d3) {
  const int z = blockIdx.z;
  const float* s = z == 0 ? s0 : z == 1 ? s1 : z == 2 ? s2 : s3;
  uint16_t* d = z == 0 ? d0 : z == 1 ? d1 : z == 2 ? d2 : d3;
  const size_t idx = ((size_t)blockIdx.x * 256 + threadIdx.x) * 8;
  *(bf16x8*)(d + idx) = cvt8(s + idx);
}

// NT GEMM + bias: C[m,n] = sum_k A[m,k]*W[n,k] + bias[n]
// BM x (NF*32) tile, BK=64, 256 threads as 2m x 2n waves, acc[BM/32][NF].
// R14: pure-bf16 both-operand global_load_lds path (A_F32=W_F32=false) is
// the m97-proven config: 0.25 KB staged / MFMA (vs 0.375 for any f32
// operand — R3 showed dur tracks staged-bytes-per-MFMA, not MFMA count).
// 128x128 QKV tile = 32KB LDS = 5 blocks/CU, zero reg staging.
// A_F32/W_F32 reg-staged paths retained for the ws_size<64MB fallback.
// LDS XOR-swizzled: conflict-free (0 measured) and contiguous rows
// (global_load_lds-compatible). m-fastest block map for XCD L2 locality.
// ROPE: fused into the bf16 epilogue for dh<32 (wave-uniform (wn+j*16)&63;
// pair partner in lane l16^1 -> shfl_xor). VT: z==2 writes C^T per-head.
template <bool A_F32, bool W_F32, bool C_F32, bool VT, bool ROPE, int BM, int NF>
__global__ __launch_bounds__(256) void gemm3_kernel(
    const void* __restrict__ A0, const void* __restrict__ W0,
    const float* __restrict__ b0, void* __restrict__ C0,
    const void* __restrict__ A1, const void* __restrict__ W1,
    const float* __restrict__ b1, void* __restrict__ C1,
    const void* __restrict__ A2, const void* __restrict__ W2,
    const float* __restrict__ b2, void* __restrict__ C2,
    int M, int N, int K) {
  constexpr int BN = NF * 32;
  constexpr int AF = BM / 32;   // A frags per wave, also A staging iters
  const int z = blockIdx.z;
  const void* Av = z == 0 ? A0 : z == 1 ? A1 : A2;
  const void* Wp = z == 0 ? W0 : z == 1 ? W1 : W2;
  const float* bias = z == 0 ? b0 : z == 1 ? b1 : b2;
  void* Cv = z == 0 ? C0 : z == 1 ? C1 : C2;

  __shared__ __align__(16) uint16_t As[BM * 64];
  __shared__ __align__(16) uint16_t Bs[BN * 64];
  const int tid = threadIdx.x;
  const int wave = tid >> 6, lane = tid & 63;
  const int quad = lane >> 4, l16 = lane & 15;
  // XCD-locality swizzle: m fastest in HW dispatch order
  const int l = blockIdx.y * gridDim.x + blockIdx.x;
  const int nmt = M / BM;
  const int bm = (l % nmt) * BM;
  const int bn = (l / nmt) * BN;
  const int wm = (wave >> 1) * (BM / 2);
  const int wn = (wave & 1) * (BN / 2);

  f32x4 acc[AF][NF] = {};

  for (int k0 = 0; k0 < K; k0 += 64) {
    bf16x8 ar[AF], wr[NF];
    if (A_F32) {
#pragma unroll
      for (int i = 0; i < AF; i++) {
        const int c = i * 256 + tid;
        const int r = c >> 3, pc = ((c & 7) ^ (r & 7)) << 3;
        ar[i] = cvt8((const float*)Av + (size_t)(bm + r) * K + k0 + pc);
      }
    }
    if (W_F32) {
#pragma unroll
      for (int i = 0; i < NF; i++) {
        const int c = i * 256 + tid;
        const int r = c >> 3, pc = ((c & 7) ^ (r & 7)) << 3;
        wr[i] = cvt8((const float*)Wp + (size_t)(bn + r) * K + k0 + pc);
      }
    }
    if (k0) __syncthreads();
#pragma unroll
    for (int i = 0; i < AF; i++) {
      const int c = i * 256 + tid;
      const int r = c >> 3, pc = ((c & 7) ^ (r & 7)) << 3;
      if (A_F32) *(bf16x8*)(As + c * 8) = ar[i];
      else async_copy16((const uint16_t*)Av + (size_t)(bm + r) * K + k0 + pc,
                        As + (i * 256 + (tid & 192)) * 8);
    }
#pragma unroll
    for (int i = 0; i < NF; i++) {
      const int c = i * 256 + tid;
      const int r = c >> 3, pc = ((c & 7) ^ (r & 7)) << 3;
      if (W_F32) *(bf16x8*)(Bs + c * 8) = wr[i];
      else async_copy16((const uint16_t*)Wp + (size_t)(bn + r) * K + k0 + pc,
                        Bs + (i * 256 + (tid & 192)) * 8);
    }
    __syncthreads();
#pragma unroll
    for (int s = 0; s < 2; s++) {
      bf16x8 af[AF], bfr[NF];
#pragma unroll
      for (int i = 0; i < AF; i++) {
        const int Ra = wm + i * 16 + l16;
        af[i] = *(const bf16x8*)(As + Ra * 64 + (((s * 4 + quad) ^ (Ra & 7)) << 3));
      }
#pragma unroll
      for (int j = 0; j < NF; j++) {
        const int Rb = wn + j * 16 + l16;
        bfr[j] = *(const bf16x8*)(Bs + Rb * 64 + (((s * 4 + quad) ^ (Rb & 7)) << 3));
      }
#pragma unroll
      for (int i = 0; i < AF; i++)
#pragma unroll
        for (int j = 0; j < NF; j++)
          acc[i][j] = __builtin_amdgcn_mfma_f32_16x16x32_bf16(af[i], bfr[j], acc[i][j], 0, 0, 0);
    }
  }
  if (VT && z == 2) {
#pragma unroll
    for (int j = 0; j < NF; j++) {
      const int n = bn + wn + j * 16 + l16;
      const float bj = bias[n];
      const int h = n >> 6, dh = n & 63;
#pragma unroll
      for (int i = 0; i < AF; i++) {
        const int m0 = bm + wm + i * 16 + quad * 4;
        const int b = m0 >> 11, s0 = m0 & 2047;
        uint2 pk;
        pk.x = (unsigned)f2bf(acc[i][j][0] + bj) |
               ((unsigned)f2bf(acc[i][j][1] + bj) << 16);
        pk.y = (unsigned)f2bf(acc[i][j][2] + bj) |
               ((unsigned)f2bf(acc[i][j][3] + bj) << 16);
        *(uint2*)((uint16_t*)Cv + ((size_t)((b * 16 + h) * 64 + dh)) * 2048 + s0) = pk;
      }
    }
  } else {
#pragma unroll
    for (int j = 0; j < NF; j++) {
      const int n = bn + wn + j * 16 + l16;
      const float bj = bias[n];
      // dh = n & 63; rot iff dh<32 — wave-uniform: ((wn + j*16) & 63) < 32
      const int dh = (wn + j * 16 + l16) & 63;
      const bool rot = ROPE && (((wn + j * 16) & 63) < 32);
      float invrev = 0.f;
      if (rot)
        invrev = __expf(-0.5756462732485115f * (float)(dh >> 1)) *
                 0.15915494309189535f;  // 10000^(-i/16) / 2pi
#pragma unroll
      for (int i = 0; i < AF; i++) {
        const int m0 = bm + wm + i * 16 + quad * 4;
#pragma unroll
        for (int r = 0; r < 4; r++) {
          float v = acc[i][j][r] + bj;
          if (rot) {
            const int s_pos = (m0 + r) & 2047;
            float rev = (float)s_pos * invrev;
            rev -= floorf(rev);
            const float sn = __builtin_amdgcn_sinf(rev);
            const float cs = __builtin_amdgcn_cosf(rev);
            const float partner = __shfl_xor(v, 1);
            v = (dh & 1) ? (v * cs + partner * sn) : (v * cs - partner * sn);
          }
          if (C_F32) ((float*)Cv)[(size_t)(m0 + r) * N + n] = v;
          else       ((uint16_t*)Cv)[(size_t)(m0 + r) * N + n] = f2bf(v);
        }
      }
    }
  }
}

// Flash attention, causal, MAX-FREE softmax (scores statically bounded ->
// exp finite; masked lanes -1e30 -> exp=0). S^T form: lane l16 owns q-row.
// R16: NO K/V LDS STAGING. R4->R5 pair showed flash is staging/barrier-
// drain-bound (occupancy 2x -> slower when staged-bytes/MFMA doubled); K/VT
// is L2-resident (2 MB/XCD via swizzle, HBM 4%) — per guide m169, staging
// L2-fit data is pure overhead. K and V fragments are loaded directly
// global->reg (16 rows x 64B contiguous segments per instr). This removes
// Ks/Vt LDS, the DMA, and ALL __syncthreads: waves are fully independent,
// compiler schedules V loads under QK^T MFMAs. Only per-wave Ps remains in
// LDS (cross-lane P redistribution; wave-private, program-order safe).
// 128 q-rows per block (2 Q-frags per wave); low frag skipped at last kt.
// XCD swizzle: bx&7 = XCD; 4 heads/XCD. Heaviest q-tiles first.
__global__ __launch_bounds__(256) void flash_kernel(const uint16_t* __restrict__ Q,
                                                    const uint16_t* __restrict__ K,
                                                    const uint16_t* __restrict__ VT,
                                                    uint16_t* __restrict__ AO) {
  const int bx = blockIdx.x;           // 512 blocks
  const int xcd = bx & 7;
  const int slot = bx >> 3;            // 0..63
  const int bh = (slot >> 4) * 8 + xcd;
  const int qt2 = 15 - (slot & 15);    // heaviest first
  const int h = bh & 15;
  const int b = bh >> 4;
  const int tid = threadIdx.x;
  const int wave = tid >> 6, lane = tid & 63;
  const int quad = lane >> 4, l16 = lane & 15;

  __shared__ __align__(16) uint16_t Ps[4][32 * 72];   // per-wave P (2 frags)

  // Q fragments (B-operand layout: lane l16 = q-row), pre-scaled by 1/8
  const int qrow0 = qt2 * 128 + wave * 16 + l16;      // frag0
  const int qrow1 = qrow0 + 64;                       // frag1
  bf16x8 qf0[2], qf1[2];
#pragma unroll
  for (int s = 0; s < 2; s++) {
    union { bf16x8 v; uint16_t u[8]; } t0, t1;
    t0.v = *(const bf16x8*)(Q + ((size_t)(b * 2048 + qrow0) * 1024) + h * 64 + s * 32 + quad * 8);
    t1.v = *(const bf16x8*)(Q + ((size_t)(b * 2048 + qrow1) * 1024) + h * 64 + s * 32 + quad * 8);
#pragma unroll
    for (int j = 0; j < 8; j++) {
      t0.u[j] = f2bf(bf2f(t0.u[j]) * 0.125f);
      t1.u[j] = f2bf(bf2f(t1.u[j]) * 0.125f);
    }
    qf0[s] = t0.v;
    qf1[s] = t1.v;
  }

  const uint16_t* Kh = K + (size_t)(b * 2048) * 1024 + h * 64;          // [s][d]
  const uint16_t* Vh = VT + ((size_t)((b * 16 + h) * 64)) * 2048;       // [d][s]

  float lsum0 = 0.f, lsum1 = 0.f;
  f32x4 o0[4] = {}, o1[4] = {};

  const int nkt = 2 * qt2 + 2;
  for (int kt = 0; kt < nkt; kt++) {
    const bool f0 = (kt < nkt - 1);  // low frag fully masked at last kt

    // ---- QK^T (K direct from L2; kf shared by both frags) ----
    f32x4 sacc1[4] = {}, sacc0[4] = {};
#pragma unroll
    for (int s = 0; s < 2; s++) {
      bf16x8 kf[4];
#pragma unroll
      for (int t = 0; t < 4; t++)
        kf[t] = *(const bf16x8*)(Kh + (size_t)(kt * 64 + t * 16 + l16) * 1024 + s * 32 + quad * 8);
#pragma unroll
      for (int t = 0; t < 4; t++)
        sacc1[t] = __builtin_amdgcn_mfma_f32_16x16x32_bf16(kf[t], qf1[s], sacc1[t], 0, 0, 0);
      if (f0) {
#pragma unroll
        for (int t = 0; t < 4; t++)
          sacc0[t] = __builtin_amdgcn_mfma_f32_16x16x32_bf16(kf[t], qf0[s], sacc0[t], 0, 0, 0);
      }
    }
    // ---- softmax numerators, P pack (frag1) ----
    if (kt == nkt - 1) {
#pragma unroll
      for (int t = 0; t < 4; t++)
#pragma unroll
        for (int r = 0; r < 4; r++)
          if (kt * 64 + t * 16 + quad * 4 + r > qrow1) sacc1[t][r] = -1e30f;
    }
#pragma unroll
    for (int t = 0; t < 4; t++) {
      float p0 = __expf(sacc1[t][0]), p1 = __expf(sacc1[t][1]);
      float p2 = __expf(sacc1[t][2]), p3 = __expf(sacc1[t][3]);
      lsum1 += (p0 + p1) + (p2 + p3);
      uint2 pk;
      pk.x = (unsigned)f2bf(p0) | ((unsigned)f2bf(p1) << 16);
      pk.y = (unsigned)f2bf(p2) | ((unsigned)f2bf(p3) << 16);
      *(uint2*)(&Ps[wave][(16 + l16) * 72 + t * 16 + quad * 4]) = pk;
    }
    // ---- frag0 ----
    if (f0) {
      if (kt == nkt - 2) {
#pragma unroll
        for (int t = 0; t < 4; t++)
#pragma unroll
          for (int r = 0; r < 4; r++)
            if (kt * 64 + t * 16 + quad * 4 + r > qrow0) sacc0[t][r] = -1e30f;
      }
#pragma unroll
      for (int t = 0; t < 4; t++) {
        float p0 = __expf(sacc0[t][0]), p1 = __expf(sacc0[t][1]);
        float p2 = __expf(sacc0[t][2]), p3 = __expf(sacc0[t][3]);
        lsum0 += (p0 + p1) + (p2 + p3);
        uint2 pk;
        pk.x = (unsigned)f2bf(p0) | ((unsigned)f2bf(p1) << 16);
        pk.y = (unsigned)f2bf(p2) | ((unsigned)f2bf(p3) << 16);
        *(uint2*)(&Ps[wave][l16 * 72 + t * 16 + quad * 4]) = pk;
      }
    }
    // ---- PV (V direct from L2; vb shared by both frags) ----
#pragma unroll
    for (int s = 0; s < 2; s++) {
      bf16x8 vb[4];
#pragma unroll
      for (int t = 0; t < 4; t++)
        vb[t] = *(const bf16x8*)(Vh + (size_t)(t * 16 + l16) * 2048 + kt * 64 + s * 32 + quad * 8);
      const bf16x8 pa1 = *(const bf16x8*)(&Ps[wave][(16 + l16) * 72 + s * 32 + quad * 8]);
#pragma unroll
      for (int t = 0; t < 4; t++)
        o1[t] = __builtin_amdgcn_mfma_f32_16x16x32_bf16(pa1, vb[t], o1[t], 0, 0, 0);
      if (f0) {
        const bf16x8 pa0 = *(const bf16x8*)(&Ps[wave][l16 * 72 + s * 32 + quad * 8]);
#pragma unroll
        for (int t = 0; t < 4; t++)
          o0[t] = __builtin_amdgcn_mfma_f32_16x16x32_bf16(pa0, vb[t], o0[t], 0, 0, 0);
      }
    }
  }
  // row-sum reduce over quads (q-row = l16); broadcast inverse to C/D rows
  lsum0 += __shfl_xor(lsum0, 16);
  lsum0 += __shfl_xor(lsum0, 32);
  lsum1 += __shfl_xor(lsum1, 16);
  lsum1 += __shfl_xor(lsum1, 32);
  const float inv0 = 1.f / lsum0, inv1 = 1.f / lsum1;
  float invr0[4], invr1[4];
#pragma unroll
  for (int r = 0; r < 4; r++) {
    invr0[r] = __shfl(inv0, quad * 4 + r);
    invr1[r] = __shfl(inv1, quad * 4 + r);
  }
#pragma unroll
  for (int t = 0; t < 4; t++)
#pragma unroll
    for (int r = 0; r < 4; r++) {
      const int qg0 = qt2 * 128 + wave * 16 + quad * 4 + r;
      AO[((size_t)(b * 2048 + qg0) * 1024) + h * 64 + t * 16 + l16] =
          f2bf(o0[t][r] * invr0[r]);
      AO[((size_t)(b * 2048 + qg0 + 64) * 1024) + h * 64 + t * 16 + l16] =
          f2bf(o1[t][r] * invr1[r]);
    }
}

extern "C" void kernel_launch(void* const* d_in, const int* in_sizes, int n_in,
                              void* d_out, int out_size, void* d_ws, size_t ws_size,
                              hipStream_t stream) {
  const float* query = (const float*)d_in[0];
  const float* key   = (const float*)d_in[1];
  const float* value = (const float*)d_in[2];
  const float* Wq = (const float*)d_in[3];
  const float* bq = (const float*)d_in[4];
  const float* Wk = (const float*)d_in[5];
  const float* bk = (const float*)d_in[6];
  const float* Wv = (const float*)d_in[7];
  const float* bv = (const float*)d_in[8];
  const float* Wo = (const float*)d_in[9];
  const float* bo = (const float*)d_in[10];
  float* out = (float*)d_out;

  uint16_t* ws = (uint16_t*)d_ws;
  uint16_t* Qb  = ws;                         // [0,8M) bytes: bf16 (roped)
  uint16_t* Kb  = ws + (size_t)4194304;       // [8M,16M) (roped)
  uint16_t* VTb = ws + (size_t)8388608;       // [16M,24M) V^T [b,h,d,s]
  uint16_t* AOb = ws + (size_t)12582912;      // [24M,32M)

  dim3 blk(256);

  if (ws_size >= (size_t)64 * 1024 * 1024) {
    // Fast path: bf16 copies of activations + all weights -> pure-DMA GEMMs.
    uint16_t* Qc  = ws + (size_t)16777216;    // [32M,40M) query bf16
    uint16_t* Kc  = ws + (size_t)20971520;    // [40M,48M) key bf16
    uint16_t* Vc  = ws + (size_t)25165824;    // [48M,56M) value bf16
    uint16_t* Wqc = ws + (size_t)29360128;    // [56M,58M)
    uint16_t* Wkc = ws + (size_t)30408704;    // [58M,60M)
    uint16_t* Wvc = ws + (size_t)31457280;    // [60M,62M)
    uint16_t* Woc = ws + (size_t)32505856;    // [62M,64M)

    cvt_kernel<<<dim3(512, 1, 4), blk, 0, stream>>>(
        Wq, Wqc, Wk, Wkc, Wv, Wvc, Wo, Woc);
    cvt_kernel<<<dim3(2048, 1, 3), blk, 0, stream>>>(
        query, Qc, key, Kc, value, Vc, nullptr, nullptr);
    // QKV: pure bf16, 128x128 tile, both operands global_load_lds,
    // 32KB LDS -> 5 blocks/CU; grid 8 n-tiles x 32 m-tiles x 3
    gemm3_kernel<false, false, false, true, true, 128, 4><<<dim3(8, 32, 3), blk, 0, stream>>>(
        Qc, Wqc, bq, Qb,
        Kc, Wkc, bk, Kb,
        Vc, Wvc, bv, VTb,
        4096, 1024, 1024);
    flash_kernel<<<dim3(512), blk, 0, stream>>>(Qb, Kb, VTb, AOb);
    // out-proj: pure bf16 128x64, both DMA, 24KB LDS -> 6 blocks/CU
    gemm3_kernel<false, false, true, false, false, 128, 2><<<dim3(16, 32, 1), blk, 0, stream>>>(
        AOb, Woc, bo, out,
        AOb, Woc, bo, out,
        AOb, Woc, bo, out,
        4096, 1024, 1024);
  } else {
    // Fallback: R0 GEMM configuration (32MB workspace).
    uint16_t* Wqc = AOb;
    uint16_t* Wkc = AOb + (size_t)1048576;
    uint16_t* Wvc = AOb + (size_t)2097152;
    cvt_kernel<<<dim3(512, 1, 3), blk, 0, stream>>>(
        Wq, Wqc, Wk, Wkc, Wv, Wvc, nullptr, nullptr);
    gemm3_kernel<true, false, false, true, true, 128, 2><<<dim3(16, 32, 3), blk, 0, stream>>>(
        query, Wqc, bq, Qb,
        key,   Wkc, bk, Kb,
        value, Wvc, bv, VTb,
        4096, 1024, 1024);
    flash_kernel<<<dim3(512), blk, 0, stream>>>(Qb, Kb, VTb, AOb);
    gemm3_kernel<false, true, true, false, false, 128, 2><<<dim3(16, 32, 1), blk, 0, stream>>>(
        AOb, Wo, bo, out,
        AOb, Wo, bo, out,
        AOb, Wo, bo, out,
        4096, 1024, 1024);
  }
}

// Round 7
// 230.447 us; speedup vs baseline: 1.2521x; 1.2521x over previous
//
#include <hip/hip_runtime.h>
#include <stdint.h>
#include <math.h>

// B=2 S=2048 E=1024 H=16 DH=64 ROT=32 CTX=2048
// d_in / d_out are FLOAT32 (per reference). Internals use bf16 MFMA.
typedef __bf16 bf16x8 __attribute__((ext_vector_type(8)));
typedef float f32x4 __attribute__((ext_vector_type(4)));

__device__ __forceinline__ float bf2f(uint16_t x) {
  unsigned u = ((unsigned)x) << 16;
  float f;
  __builtin_memcpy(&f, &u, 4);
  return f;
}
// native RTNE f32->bf16
__device__ __forceinline__ uint16_t f2bf(float f) {
  __bf16 h = (__bf16)f;
  uint16_t u;
  __builtin_memcpy(&u, &h, 2);
  return u;
}
// round two float4s to bf16x8
__device__ __forceinline__ bf16x8 pack8(float4 lo, float4 hi) {
  bf16x8 v;
  v[0] = (__bf16)lo.x; v[1] = (__bf16)lo.y; v[2] = (__bf16)lo.z; v[3] = (__bf16)lo.w;
  v[4] = (__bf16)hi.x; v[5] = (__bf16)hi.y; v[6] = (__bf16)hi.z; v[7] = (__bf16)hi.w;
  return v;
}
// load 8 contiguous f32, round to bf16x8
__device__ __forceinline__ bf16x8 cvt8(const float* p) {
  return pack8(*(const float4*)p, *(const float4*)(p + 4));
}

// direct global->LDS, 16B/lane; LDS dest = wave-uniform base + lane*16
typedef __attribute__((address_space(1))) const unsigned int gu32;
typedef __attribute__((address_space(3))) unsigned int lu32;
__device__ __forceinline__ void async_copy16(const void* gp, void* lp) {
  __builtin_amdgcn_global_load_lds((gu32*)gp, (lu32*)lp, 16, 0, 0);
}

// f32 -> bf16 elementwise convert; grid.z selects tensor, grid.x*256*8 = count
__global__ __launch_bounds__(256) void cvt_kernel(
    const float* __restrict__ s0, uint16_t* __restrict__ d0,
    const float* __restrict__ s1, uint16_t* __restrict__ d1,
    const float* __restrict__ s2, uint16_t* __restrict__ d2,
    const float* __restrict__ s3, uint16_t* __restrict__ d3) {
  const int z = blockIdx.z;
  const float* s = z == 0 ? s0 : z == 1 ? s1 : z == 2 ? s2 : s3;
  uint16_t* d = z == 0 ? d0 : z == 1 ? d1 : z == 2 ? d2 : d3;
  const size_t idx = ((size_t)blockIdx.x * 256 + threadIdx.x) * 8;
  *(bf16x8*)(d + idx) = cvt8(s + idx);
}

// NT GEMM + bias: C[m,n] = sum_k A[m,k]*W[n,k] + bias[n]
// BM x (NF*32) tile, BK=64, 256 threads as 2m x 2n waves, acc[BM/32][NF].
// R14: pure-bf16 both-operand global_load_lds path (A_F32=W_F32=false) is
// the m97-proven config: 0.25 KB staged / MFMA (vs 0.375 for any f32
// operand — R3 showed dur tracks staged-bytes-per-MFMA, not MFMA count).
// 128x128 QKV tile = 32KB LDS = 5 blocks/CU, zero reg staging.
// A_F32/W_F32 reg-staged paths retained for the ws_size<64MB fallback.
// LDS XOR-swizzled: conflict-free (0 measured) and contiguous rows
// (global_load_lds-compatible). m-fastest block map for XCD L2 locality.
// ROPE: fused into the bf16 epilogue for dh<32 (wave-uniform (wn+j*16)&63;
// pair partner in lane l16^1 -> shfl_xor). VT: z==2 writes C^T per-head.
template <bool A_F32, bool W_F32, bool C_F32, bool VT, bool ROPE, int BM, int NF>
__global__ __launch_bounds__(256) void gemm3_kernel(
    const void* __restrict__ A0, const void* __restrict__ W0,
    const float* __restrict__ b0, void* __restrict__ C0,
    const void* __restrict__ A1, const void* __restrict__ W1,
    const float* __restrict__ b1, void* __restrict__ C1,
    const void* __restrict__ A2, const void* __restrict__ W2,
    const float* __restrict__ b2, void* __restrict__ C2,
    int M, int N, int K) {
  constexpr int BN = NF * 32;
  constexpr int AF = BM / 32;   // A frags per wave, also A staging iters
  const int z = blockIdx.z;
  const void* Av = z == 0 ? A0 : z == 1 ? A1 : A2;
  const void* Wp = z == 0 ? W0 : z == 1 ? W1 : W2;
  const float* bias = z == 0 ? b0 : z == 1 ? b1 : b2;
  void* Cv = z == 0 ? C0 : z == 1 ? C1 : C2;

  __shared__ __align__(16) uint16_t As[BM * 64];
  __shared__ __align__(16) uint16_t Bs[BN * 64];
  const int tid = threadIdx.x;
  const int wave = tid >> 6, lane = tid & 63;
  const int quad = lane >> 4, l16 = lane & 15;
  // XCD-locality swizzle: m fastest in HW dispatch order
  const int l = blockIdx.y * gridDim.x + blockIdx.x;
  const int nmt = M / BM;
  const int bm = (l % nmt) * BM;
  const int bn = (l / nmt) * BN;
  const int wm = (wave >> 1) * (BM / 2);
  const int wn = (wave & 1) * (BN / 2);

  f32x4 acc[AF][NF] = {};

  for (int k0 = 0; k0 < K; k0 += 64) {
    bf16x8 ar[AF], wr[NF];
    if (A_F32) {
#pragma unroll
      for (int i = 0; i < AF; i++) {
        const int c = i * 256 + tid;
        const int r = c >> 3, pc = ((c & 7) ^ (r & 7)) << 3;
        ar[i] = cvt8((const float*)Av + (size_t)(bm + r) * K + k0 + pc);
      }
    }
    if (W_F32) {
#pragma unroll
      for (int i = 0; i < NF; i++) {
        const int c = i * 256 + tid;
        const int r = c >> 3, pc = ((c & 7) ^ (r & 7)) << 3;
        wr[i] = cvt8((const float*)Wp + (size_t)(bn + r) * K + k0 + pc);
      }
    }
    if (k0) __syncthreads();
#pragma unroll
    for (int i = 0; i < AF; i++) {
      const int c = i * 256 + tid;
      const int r = c >> 3, pc = ((c & 7) ^ (r & 7)) << 3;
      if (A_F32) *(bf16x8*)(As + c * 8) = ar[i];
      else async_copy16((const uint16_t*)Av + (size_t)(bm + r) * K + k0 + pc,
                        As + (i * 256 + (tid & 192)) * 8);
    }
#pragma unroll
    for (int i = 0; i < NF; i++) {
      const int c = i * 256 + tid;
      const int r = c >> 3, pc = ((c & 7) ^ (r & 7)) << 3;
      if (W_F32) *(bf16x8*)(Bs + c * 8) = wr[i];
      else async_copy16((const uint16_t*)Wp + (size_t)(bn + r) * K + k0 + pc,
                        Bs + (i * 256 + (tid & 192)) * 8);
    }
    __syncthreads();
#pragma unroll
    for (int s = 0; s < 2; s++) {
      bf16x8 af[AF], bfr[NF];
#pragma unroll
      for (int i = 0; i < AF; i++) {
        const int Ra = wm + i * 16 + l16;
        af[i] = *(const bf16x8*)(As + Ra * 64 + (((s * 4 + quad) ^ (Ra & 7)) << 3));
      }
#pragma unroll
      for (int j = 0; j < NF; j++) {
        const int Rb = wn + j * 16 + l16;
        bfr[j] = *(const bf16x8*)(Bs + Rb * 64 + (((s * 4 + quad) ^ (Rb & 7)) << 3));
      }
#pragma unroll
      for (int i = 0; i < AF; i++)
#pragma unroll
        for (int j = 0; j < NF; j++)
          acc[i][j] = __builtin_amdgcn_mfma_f32_16x16x32_bf16(af[i], bfr[j], acc[i][j], 0, 0, 0);
    }
  }
  if (VT && z == 2) {
#pragma unroll
    for (int j = 0; j < NF; j++) {
      const int n = bn + wn + j * 16 + l16;
      const float bj = bias[n];
      const int h = n >> 6, dh = n & 63;
#pragma unroll
      for (int i = 0; i < AF; i++) {
        const int m0 = bm + wm + i * 16 + quad * 4;
        const int b = m0 >> 11, s0 = m0 & 2047;
        uint2 pk;
        pk.x = (unsigned)f2bf(acc[i][j][0] + bj) |
               ((unsigned)f2bf(acc[i][j][1] + bj) << 16);
        pk.y = (unsigned)f2bf(acc[i][j][2] + bj) |
               ((unsigned)f2bf(acc[i][j][3] + bj) << 16);
        *(uint2*)((uint16_t*)Cv + ((size_t)((b * 16 + h) * 64 + dh)) * 2048 + s0) = pk;
      }
    }
  } else {
#pragma unroll
    for (int j = 0; j < NF; j++) {
      const int n = bn + wn + j * 16 + l16;
      const float bj = bias[n];
      // dh = n & 63; rot iff dh<32 — wave-uniform: ((wn + j*16) & 63) < 32
      const int dh = (wn + j * 16 + l16) & 63;
      const bool rot = ROPE && (((wn + j * 16) & 63) < 32);
      float invrev = 0.f;
      if (rot)
        invrev = __expf(-0.5756462732485115f * (float)(dh >> 1)) *
                 0.15915494309189535f;  // 10000^(-i/16) / 2pi
#pragma unroll
      for (int i = 0; i < AF; i++) {
        const int m0 = bm + wm + i * 16 + quad * 4;
#pragma unroll
        for (int r = 0; r < 4; r++) {
          float v = acc[i][j][r] + bj;
          if (rot) {
            const int s_pos = (m0 + r) & 2047;
            float rev = (float)s_pos * invrev;
            rev -= floorf(rev);
            const float sn = __builtin_amdgcn_sinf(rev);
            const float cs = __builtin_amdgcn_cosf(rev);
            const float partner = __shfl_xor(v, 1);
            v = (dh & 1) ? (v * cs + partner * sn) : (v * cs - partner * sn);
          }
          if (C_F32) ((float*)Cv)[(size_t)(m0 + r) * N + n] = v;
          else       ((uint16_t*)Cv)[(size_t)(m0 + r) * N + n] = f2bf(v);
        }
      }
    }
  }
}

// Flash attention, causal, MAX-FREE softmax (scores statically bounded ->
// exp finite; masked lanes -1e30 -> exp=0). S^T form: lane l16 owns q-row
// l16; P pack = 4x ds_write_b64; one scalar row-sum per frag.
// R17: double-buffered K/V staging (T3 minimum-2-phase). R4 counters
// (MfmaUtil 10.5 + VALUBusy 28, ~60% idle) showed the serial
// barrier->DMA->barrier->compute structure exposes full DMA latency each
// kt. Now: issue next tile's global_load_lds BEFORE computing current
// tile; ONE __syncthreads per kt (its builtin vmcnt(0) drain waits on
// loads that had the whole compute phase to land). R6 proved staging
// itself is required (4-wave K/V sharing via LDS: removing it = 4x L2
// traffic + scattered loads -> 2x slower).
// 128 q-rows per block (2 Q-frags per wave); low frag skipped at last kt.
// XCD swizzle: bx&7 = XCD; 4 heads/XCD -> 2 MB K/VT L2-resident.
// Heaviest q-tiles dispatched first. LDS 50KB (2x8 K + 2x8 V + 18 Ps).
__global__ __launch_bounds__(256) void flash_kernel(const uint16_t* __restrict__ Q,
                                                    const uint16_t* __restrict__ K,
                                                    const uint16_t* __restrict__ VT,
                                                    uint16_t* __restrict__ AO) {
  const int bx = blockIdx.x;           // 512 blocks
  const int xcd = bx & 7;
  const int slot = bx >> 3;            // 0..63
  const int bh = (slot >> 4) * 8 + xcd;
  const int qt2 = 15 - (slot & 15);    // heaviest first
  const int h = bh & 15;
  const int b = bh >> 4;
  const int tid = threadIdx.x;
  const int wave = tid >> 6, lane = tid & 63;
  const int quad = lane >> 4, l16 = lane & 15;

  __shared__ __align__(16) uint16_t Ks[2][64 * 64];   // [n][d] swizzled, 2x8KB
  __shared__ __align__(16) uint16_t Vt[2][64 * 64];   // [d][n] swizzled, 2x8KB
  __shared__ __align__(16) uint16_t Ps[4][32 * 72];   // per-wave P, 18KB

  // Q fragments (B-operand layout: lane l16 = q-row), pre-scaled by 1/8
  const int qrow0 = qt2 * 128 + wave * 16 + l16;      // frag0
  const int qrow1 = qrow0 + 64;                       // frag1
  bf16x8 qf0[2], qf1[2];
#pragma unroll
  for (int s = 0; s < 2; s++) {
    union { bf16x8 v; uint16_t u[8]; } t0, t1;
    t0.v = *(const bf16x8*)(Q + ((size_t)(b * 2048 + qrow0) * 1024) + h * 64 + s * 32 + quad * 8);
    t1.v = *(const bf16x8*)(Q + ((size_t)(b * 2048 + qrow1) * 1024) + h * 64 + s * 32 + quad * 8);
#pragma unroll
    for (int j = 0; j < 8; j++) {
      t0.u[j] = f2bf(bf2f(t0.u[j]) * 0.125f);
      t1.u[j] = f2bf(bf2f(t1.u[j]) * 0.125f);
    }
    qf0[s] = t0.v;
    qf1[s] = t1.v;
  }

  const size_t vbase = ((size_t)((b * 16 + h) * 64)) * 2048;  // VT head base

  // stage K/V tile kt into buffer buf (one contiguous 1KB segment / instr)
  auto stage = [&](int buf, int kt) {
#pragma unroll
    for (int i = 0; i < 2; i++) {
      const int c = i * 256 + tid;
      const int r = c >> 3, pc = ((c & 7) ^ (r & 7)) << 3;
      async_copy16(K + ((size_t)(b * 2048 + kt * 64 + r) * 1024) + h * 64 + pc,
                   Ks[buf] + (i * 256 + (tid & 192)) * 8);
      async_copy16(VT + vbase + (size_t)r * 2048 + kt * 64 + pc,
                   Vt[buf] + (i * 256 + (tid & 192)) * 8);
    }
  };

  float lsum0 = 0.f, lsum1 = 0.f;
  f32x4 o0[4] = {}, o1[4] = {};

  const int nkt = 2 * qt2 + 2;
  stage(0, 0);
  __syncthreads();   // drains vmcnt(0) + barrier: buf0 ready
  int cur = 0;
  for (int kt = 0; kt < nkt; kt++) {
    // issue next tile's DMA first: latency hides under this kt's compute
    if (kt + 1 < nkt) stage(cur ^ 1, kt + 1);
    const uint16_t* ksp = Ks[cur];
    const uint16_t* vtp = Vt[cur];

    const bool f0 = (kt < nkt - 1);  // low frag fully masked at last kt

    // ---- frag1 S^T ----
    {
      f32x4 sacc[4] = {};
#pragma unroll
      for (int s = 0; s < 2; s++)
#pragma unroll
        for (int t = 0; t < 4; t++) {
          const int R = t * 16 + l16;
          bf16x8 kf = *(const bf16x8*)(ksp + R * 64 + (((s * 4 + quad) ^ (R & 7)) << 3));
          sacc[t] = __builtin_amdgcn_mfma_f32_16x16x32_bf16(kf, qf1[s], sacc[t], 0, 0, 0);
        }
      if (kt == nkt - 1) {
#pragma unroll
        for (int t = 0; t < 4; t++)
#pragma unroll
          for (int r = 0; r < 4; r++)
            if (kt * 64 + t * 16 + quad * 4 + r > qrow1) sacc[t][r] = -1e30f;
      }
#pragma unroll
      for (int t = 0; t < 4; t++) {
        float p0 = __expf(sacc[t][0]), p1 = __expf(sacc[t][1]);
        float p2 = __expf(sacc[t][2]), p3 = __expf(sacc[t][3]);
        lsum1 += (p0 + p1) + (p2 + p3);
        uint2 pk;
        pk.x = (unsigned)f2bf(p0) | ((unsigned)f2bf(p1) << 16);
        pk.y = (unsigned)f2bf(p2) | ((unsigned)f2bf(p3) << 16);
        *(uint2*)(&Ps[wave][(16 + l16) * 72 + t * 16 + quad * 4]) = pk;
      }
    }
    // ---- frag0 S^T ----
    if (f0) {
      f32x4 sacc[4] = {};
#pragma unroll
      for (int s = 0; s < 2; s++)
#pragma unroll
        for (int t = 0; t < 4; t++) {
          const int R = t * 16 + l16;
          bf16x8 kf = *(const bf16x8*)(ksp + R * 64 + (((s * 4 + quad) ^ (R & 7)) << 3));
          sacc[t] = __builtin_amdgcn_mfma_f32_16x16x32_bf16(kf, qf0[s], sacc[t], 0, 0, 0);
        }
      if (kt == nkt - 2) {
#pragma unroll
        for (int t = 0; t < 4; t++)
#pragma unroll
          for (int r = 0; r < 4; r++)
            if (kt * 64 + t * 16 + quad * 4 + r > qrow0) sacc[t][r] = -1e30f;
      }
#pragma unroll
      for (int t = 0; t < 4; t++) {
        float p0 = __expf(sacc[t][0]), p1 = __expf(sacc[t][1]);
        float p2 = __expf(sacc[t][2]), p3 = __expf(sacc[t][3]);
        lsum0 += (p0 + p1) + (p2 + p3);
        uint2 pk;
        pk.x = (unsigned)f2bf(p0) | ((unsigned)f2bf(p1) << 16);
        pk.y = (unsigned)f2bf(p2) | ((unsigned)f2bf(p3) << 16);
        *(uint2*)(&Ps[wave][l16 * 72 + t * 16 + quad * 4]) = pk;
      }
    }
    // ---- PV ----
#pragma unroll
    for (int s = 0; s < 2; s++) {
      const bf16x8 pa1 = *(const bf16x8*)(&Ps[wave][(16 + l16) * 72 + s * 32 + quad * 8]);
#pragma unroll
      for (int t = 0; t < 4; t++) {
        const int R = t * 16 + l16;
        const bf16x8 vb = *(const bf16x8*)(vtp + R * 64 + (((s * 4 + quad) ^ (R & 7)) << 3));
        o1[t] = __builtin_amdgcn_mfma_f32_16x16x32_bf16(pa1, vb, o1[t], 0, 0, 0);
      }
    }
    if (f0) {
#pragma unroll
      for (int s = 0; s < 2; s++) {
        const bf16x8 pa0 = *(const bf16x8*)(&Ps[wave][l16 * 72 + s * 32 + quad * 8]);
#pragma unroll
        for (int t = 0; t < 4; t++) {
          const int R = t * 16 + l16;
          const bf16x8 vb = *(const bf16x8*)(vtp + R * 64 + (((s * 4 + quad) ^ (R & 7)) << 3));
          o0[t] = __builtin_amdgcn_mfma_f32_16x16x32_bf16(pa0, vb, o0[t], 0, 0, 0);
        }
      }
    }
    if (kt + 1 < nkt) {
      // single barrier per kt: its vmcnt(0) drain covers the stage() issued
      // at the top (had the whole compute phase to land); also guards the
      // buffer we stage into next iter (all waves done reading it).
      __syncthreads();
      cur ^= 1;
    }
  }
  // row-sum reduce over quads (q-row = l16); broadcast inverse to C/D rows
  lsum0 += __shfl_xor(lsum0, 16);
  lsum0 += __shfl_xor(lsum0, 32);
  lsum1 += __shfl_xor(lsum1, 16);
  lsum1 += __shfl_xor(lsum1, 32);
  const float inv0 = 1.f / lsum0, inv1 = 1.f / lsum1;
  float invr0[4], invr1[4];
#pragma unroll
  for (int r = 0; r < 4; r++) {
    invr0[r] = __shfl(inv0, quad * 4 + r);
    invr1[r] = __shfl(inv1, quad * 4 + r);
  }
#pragma unroll
  for (int t = 0; t < 4; t++)
#pragma unroll
    for (int r = 0; r < 4; r++) {
      const int qg0 = qt2 * 128 + wave * 16 + quad * 4 + r;
      AO[((size_t)(b * 2048 + qg0) * 1024) + h * 64 + t * 16 + l16] =
          f2bf(o0[t][r] * invr0[r]);
      AO[((size_t)(b * 2048 + qg0 + 64) * 1024) + h * 64 + t * 16 + l16] =
          f2bf(o1[t][r] * invr1[r]);
    }
}

extern "C" void kernel_launch(void* const* d_in, const int* in_sizes, int n_in,
                              void* d_out, int out_size, void* d_ws, size_t ws_size,
                              hipStream_t stream) {
  const float* query = (const float*)d_in[0];
  const float* key   = (const float*)d_in[1];
  const float* value = (const float*)d_in[2];
  const float* Wq = (const float*)d_in[3];
  const float* bq = (const float*)d_in[4];
  const float* Wk = (const float*)d_in[5];
  const float* bk = (const float*)d_in[6];
  const float* Wv = (const float*)d_in[7];
  const float* bv = (const float*)d_in[8];
  const float* Wo = (const float*)d_in[9];
  const float* bo = (const float*)d_in[10];
  float* out = (float*)d_out;

  uint16_t* ws = (uint16_t*)d_ws;
  uint16_t* Qb  = ws;                         // [0,8M) bytes: bf16 (roped)
  uint16_t* Kb  = ws + (size_t)4194304;       // [8M,16M) (roped)
  uint16_t* VTb = ws + (size_t)8388608;       // [16M,24M) V^T [b,h,d,s]
  uint16_t* AOb = ws + (size_t)12582912;      // [24M,32M)

  dim3 blk(256);

  if (ws_size >= (size_t)64 * 1024 * 1024) {
    // Fast path: bf16 copies of activations + all weights -> pure-DMA GEMMs.
    uint16_t* Qc  = ws + (size_t)16777216;    // [32M,40M) query bf16
    uint16_t* Kc  = ws + (size_t)20971520;    // [40M,48M) key bf16
    uint16_t* Vc  = ws + (size_t)25165824;    // [48M,56M) value bf16
    uint16_t* Wqc = ws + (size_t)29360128;    // [56M,58M)
    uint16_t* Wkc = ws + (size_t)30408704;    // [58M,60M)
    uint16_t* Wvc = ws + (size_t)31457280;    // [60M,62M)
    uint16_t* Woc = ws + (size_t)32505856;    // [62M,64M)

    cvt_kernel<<<dim3(512, 1, 4), blk, 0, stream>>>(
        Wq, Wqc, Wk, Wkc, Wv, Wvc, Wo, Woc);
    cvt_kernel<<<dim3(2048, 1, 3), blk, 0, stream>>>(
        query, Qc, key, Kc, value, Vc, nullptr, nullptr);
    // QKV: pure bf16, 128x128 tile, both operands global_load_lds,
    // 32KB LDS -> 5 blocks/CU; grid 8 n-tiles x 32 m-tiles x 3
    gemm3_kernel<false, false, false, true, true, 128, 4><<<dim3(8, 32, 3), blk, 0, stream>>>(
        Qc, Wqc, bq, Qb,
        Kc, Wkc, bk, Kb,
        Vc, Wvc, bv, VTb,
        4096, 1024, 1024);
    flash_kernel<<<dim3(512), blk, 0, stream>>>(Qb, Kb, VTb, AOb);
    // out-proj: pure bf16 128x64, both DMA, 24KB LDS -> 6 blocks/CU
    gemm3_kernel<false, false, true, false, false, 128, 2><<<dim3(16, 32, 1), blk, 0, stream>>>(
        AOb, Woc, bo, out,
        AOb, Woc, bo, out,
        AOb, Woc, bo, out,
        4096, 1024, 1024);
  } else {
    // Fallback: R0 GEMM configuration (32MB workspace).
    uint16_t* Wqc = AOb;
    uint16_t* Wkc = AOb + (size_t)1048576;
    uint16_t* Wvc = AOb + (size_t)2097152;
    cvt_kernel<<<dim3(512, 1, 3), blk, 0, stream>>>(
        Wq, Wqc, Wk, Wkc, Wv, Wvc, nullptr, nullptr);
    gemm3_kernel<true, false, false, true, true, 128, 2><<<dim3(16, 32, 3), blk, 0, stream>>>(
        query, Wqc, bq, Qb,
        key,   Wkc, bk, Kb,
        value, Wvc, bv, VTb,
        4096, 1024, 1024);
    flash_kernel<<<dim3(512), blk, 0, stream>>>(Qb, Kb, VTb, AOb);
    gemm3_kernel<false, true, true, false, false, 128, 2><<<dim3(16, 32, 1), blk, 0, stream>>>(
        AOb, Wo, bo, out,
        AOb, Wo, bo, out,
        AOb, Wo, bo, out,
        4096, 1024, 1024);
  }
}

// Round 8
// 224.425 us; speedup vs baseline: 1.2857x; 1.0268x over previous
//
#include <hip/hip_runtime.h>
#include <stdint.h>
#include <math.h>

// B=2 S=2048 E=1024 H=16 DH=64 ROT=32 CTX=2048
// d_in / d_out are FLOAT32 (per reference). Internals use bf16 MFMA.
typedef __bf16 bf16x8 __attribute__((ext_vector_type(8)));
typedef float f32x4 __attribute__((ext_vector_type(4)));

__device__ __forceinline__ float bf2f(uint16_t x) {
  unsigned u = ((unsigned)x) << 16;
  float f;
  __builtin_memcpy(&f, &u, 4);
  return f;
}
// native RTNE f32->bf16
__device__ __forceinline__ uint16_t f2bf(float f) {
  __bf16 h = (__bf16)f;
  uint16_t u;
  __builtin_memcpy(&u, &h, 2);
  return u;
}
// round two float4s to bf16x8
__device__ __forceinline__ bf16x8 pack8(float4 lo, float4 hi) {
  bf16x8 v;
  v[0] = (__bf16)lo.x; v[1] = (__bf16)lo.y; v[2] = (__bf16)lo.z; v[3] = (__bf16)lo.w;
  v[4] = (__bf16)hi.x; v[5] = (__bf16)hi.y; v[6] = (__bf16)hi.z; v[7] = (__bf16)hi.w;
  return v;
}
// load 8 contiguous f32, round to bf16x8
__device__ __forceinline__ bf16x8 cvt8(const float* p) {
  return pack8(*(const float4*)p, *(const float4*)(p + 4));
}

// direct global->LDS, 16B/lane; LDS dest = wave-uniform base + lane*16
typedef __attribute__((address_space(1))) const unsigned int gu32;
typedef __attribute__((address_space(3))) unsigned int lu32;
__device__ __forceinline__ void async_copy16(const void* gp, void* lp) {
  __builtin_amdgcn_global_load_lds((gu32*)gp, (lu32*)lp, 16, 0, 0);
}

// f32 -> bf16 elementwise convert; grid.z selects tensor, grid.x*256*8 = count
__global__ __launch_bounds__(256) void cvt_kernel(
    const float* __restrict__ s0, uint16_t* __restrict__ d0,
    const float* __restrict__ s1, uint16_t* __restrict__ d1,
    const float* __restrict__ s2, uint16_t* __restrict__ d2,
    const float* __restrict__ s3, uint16_t* __restrict__ d3) {
  const int z = blockIdx.z;
  const float* s = z == 0 ? s0 : z == 1 ? s1 : z == 2 ? s2 : s3;
  uint16_t* d = z == 0 ? d0 : z == 1 ? d1 : z == 2 ? d2 : d3;
  const size_t idx = ((size_t)blockIdx.x * 256 + threadIdx.x) * 8;
  *(bf16x8*)(d + idx) = cvt8(s + idx);
}

// NT GEMM + bias: C[m,n] = sum_k A[m,k]*W[n,k] + bias[n]
// BM x (NF*32) tile, BK=64, 256 threads as 2m x 2n waves, acc[BM/32][NF].
// R14: pure-bf16 both-operand global_load_lds path (A_F32=W_F32=false) is
// the m97-proven config: 0.25 KB staged / MFMA (vs 0.375 for any f32
// operand — R3 showed dur tracks staged-bytes-per-MFMA, not MFMA count).
// 128x128 QKV tile = 32KB LDS = 5 blocks/CU, zero reg staging.
// A_F32/W_F32 reg-staged paths retained for the ws_size<64MB fallback.
// LDS XOR-swizzled: conflict-free (0 measured) and contiguous rows
// (global_load_lds-compatible). m-fastest block map for XCD L2 locality.
// ROPE: fused into the bf16 epilogue for dh<32 (wave-uniform (wn+j*16)&63;
// pair partner in lane l16^1 -> shfl_xor). VT: z==2 writes C^T per-head.
template <bool A_F32, bool W_F32, bool C_F32, bool VT, bool ROPE, int BM, int NF>
__global__ __launch_bounds__(256) void gemm3_kernel(
    const void* __restrict__ A0, const void* __restrict__ W0,
    const float* __restrict__ b0, void* __restrict__ C0,
    const void* __restrict__ A1, const void* __restrict__ W1,
    const float* __restrict__ b1, void* __restrict__ C1,
    const void* __restrict__ A2, const void* __restrict__ W2,
    const float* __restrict__ b2, void* __restrict__ C2,
    int M, int N, int K) {
  constexpr int BN = NF * 32;
  constexpr int AF = BM / 32;   // A frags per wave, also A staging iters
  const int z = blockIdx.z;
  const void* Av = z == 0 ? A0 : z == 1 ? A1 : A2;
  const void* Wp = z == 0 ? W0 : z == 1 ? W1 : W2;
  const float* bias = z == 0 ? b0 : z == 1 ? b1 : b2;
  void* Cv = z == 0 ? C0 : z == 1 ? C1 : C2;

  __shared__ __align__(16) uint16_t As[BM * 64];
  __shared__ __align__(16) uint16_t Bs[BN * 64];
  const int tid = threadIdx.x;
  const int wave = tid >> 6, lane = tid & 63;
  const int quad = lane >> 4, l16 = lane & 15;
  // XCD-locality swizzle: m fastest in HW dispatch order
  const int l = blockIdx.y * gridDim.x + blockIdx.x;
  const int nmt = M / BM;
  const int bm = (l % nmt) * BM;
  const int bn = (l / nmt) * BN;
  const int wm = (wave >> 1) * (BM / 2);
  const int wn = (wave & 1) * (BN / 2);

  f32x4 acc[AF][NF] = {};

  for (int k0 = 0; k0 < K; k0 += 64) {
    bf16x8 ar[AF], wr[NF];
    if (A_F32) {
#pragma unroll
      for (int i = 0; i < AF; i++) {
        const int c = i * 256 + tid;
        const int r = c >> 3, pc = ((c & 7) ^ (r & 7)) << 3;
        ar[i] = cvt8((const float*)Av + (size_t)(bm + r) * K + k0 + pc);
      }
    }
    if (W_F32) {
#pragma unroll
      for (int i = 0; i < NF; i++) {
        const int c = i * 256 + tid;
        const int r = c >> 3, pc = ((c & 7) ^ (r & 7)) << 3;
        wr[i] = cvt8((const float*)Wp + (size_t)(bn + r) * K + k0 + pc);
      }
    }
    if (k0) __syncthreads();
#pragma unroll
    for (int i = 0; i < AF; i++) {
      const int c = i * 256 + tid;
      const int r = c >> 3, pc = ((c & 7) ^ (r & 7)) << 3;
      if (A_F32) *(bf16x8*)(As + c * 8) = ar[i];
      else async_copy16((const uint16_t*)Av + (size_t)(bm + r) * K + k0 + pc,
                        As + (i * 256 + (tid & 192)) * 8);
    }
#pragma unroll
    for (int i = 0; i < NF; i++) {
      const int c = i * 256 + tid;
      const int r = c >> 3, pc = ((c & 7) ^ (r & 7)) << 3;
      if (W_F32) *(bf16x8*)(Bs + c * 8) = wr[i];
      else async_copy16((const uint16_t*)Wp + (size_t)(bn + r) * K + k0 + pc,
                        Bs + (i * 256 + (tid & 192)) * 8);
    }
    __syncthreads();
#pragma unroll
    for (int s = 0; s < 2; s++) {
      bf16x8 af[AF], bfr[NF];
#pragma unroll
      for (int i = 0; i < AF; i++) {
        const int Ra = wm + i * 16 + l16;
        af[i] = *(const bf16x8*)(As + Ra * 64 + (((s * 4 + quad) ^ (Ra & 7)) << 3));
      }
#pragma unroll
      for (int j = 0; j < NF; j++) {
        const int Rb = wn + j * 16 + l16;
        bfr[j] = *(const bf16x8*)(Bs + Rb * 64 + (((s * 4 + quad) ^ (Rb & 7)) << 3));
      }
#pragma unroll
      for (int i = 0; i < AF; i++)
#pragma unroll
        for (int j = 0; j < NF; j++)
          acc[i][j] = __builtin_amdgcn_mfma_f32_16x16x32_bf16(af[i], bfr[j], acc[i][j], 0, 0, 0);
    }
  }
  if (VT && z == 2) {
#pragma unroll
    for (int j = 0; j < NF; j++) {
      const int n = bn + wn + j * 16 + l16;
      const float bj = bias[n];
      const int h = n >> 6, dh = n & 63;
#pragma unroll
      for (int i = 0; i < AF; i++) {
        const int m0 = bm + wm + i * 16 + quad * 4;
        const int b = m0 >> 11, s0 = m0 & 2047;
        uint2 pk;
        pk.x = (unsigned)f2bf(acc[i][j][0] + bj) |
               ((unsigned)f2bf(acc[i][j][1] + bj) << 16);
        pk.y = (unsigned)f2bf(acc[i][j][2] + bj) |
               ((unsigned)f2bf(acc[i][j][3] + bj) << 16);
        *(uint2*)((uint16_t*)Cv + ((size_t)((b * 16 + h) * 64 + dh)) * 2048 + s0) = pk;
      }
    }
  } else {
#pragma unroll
    for (int j = 0; j < NF; j++) {
      const int n = bn + wn + j * 16 + l16;
      const float bj = bias[n];
      // dh = n & 63; rot iff dh<32 — wave-uniform: ((wn + j*16) & 63) < 32
      const int dh = (wn + j * 16 + l16) & 63;
      const bool rot = ROPE && (((wn + j * 16) & 63) < 32);
      float invrev = 0.f;
      if (rot)
        invrev = __expf(-0.5756462732485115f * (float)(dh >> 1)) *
                 0.15915494309189535f;  // 10000^(-i/16) / 2pi
#pragma unroll
      for (int i = 0; i < AF; i++) {
        const int m0 = bm + wm + i * 16 + quad * 4;
#pragma unroll
        for (int r = 0; r < 4; r++) {
          float v = acc[i][j][r] + bj;
          if (rot) {
            const int s_pos = (m0 + r) & 2047;
            float rev = (float)s_pos * invrev;
            rev -= floorf(rev);
            const float sn = __builtin_amdgcn_sinf(rev);
            const float cs = __builtin_amdgcn_cosf(rev);
            const float partner = __shfl_xor(v, 1);
            v = (dh & 1) ? (v * cs + partner * sn) : (v * cs - partner * sn);
          }
          if (C_F32) ((float*)Cv)[(size_t)(m0 + r) * N + n] = v;
          else       ((uint16_t*)Cv)[(size_t)(m0 + r) * N + n] = f2bf(v);
        }
      }
    }
  }
}

// Flash attention, causal, MAX-FREE softmax (scores statically bounded ->
// exp finite; masked lanes -1e30 -> exp=0). S^T form: lane l16 owns q-row
// l16; P pack = 4x ds_write_b64; one scalar row-sum per frag.
// R18: COMPLEMENTARY-PAIR LOAD BALANCE. R4-R7 arithmetic: grid = 512 = 2
// blocks/CU, ALL co-resident at t=0 (no work-stealing possible). Old map
// gave co-resident slots (s, s+32) the SAME qt2 -> CU work ranged 4..64
// kt-iters (slowest CU = 1.9x mean = kernel duration; occupancy 11%).
// New map: slots 0-31 qt2 descending, slots 32-63 qt2 ascending -> every
// co-resident pair totals exactly 36 kt. bh set per XCD unchanged (K/VT
// stays L2-resident). Flash body = R4's measured-best single-buffer form.
// 128 q-rows per block (2 Q-frags per wave); low frag skipped at last kt.
__global__ __launch_bounds__(256) void flash_kernel(const uint16_t* __restrict__ Q,
                                                    const uint16_t* __restrict__ K,
                                                    const uint16_t* __restrict__ VT,
                                                    uint16_t* __restrict__ AO) {
  const int bx = blockIdx.x;           // 512 blocks
  const int xcd = bx & 7;
  const int slot = bx >> 3;            // 0..63 within XCD
  const int bh = (slot >> 4) * 8 + xcd;
  // complementary pairing: slot s (desc) and s+32 (asc) sum to 36 kt
  const int qt2 = (slot < 32) ? (15 - (slot & 15)) : (slot & 15);
  const int h = bh & 15;
  const int b = bh >> 4;
  const int tid = threadIdx.x;
  const int wave = tid >> 6, lane = tid & 63;
  const int quad = lane >> 4, l16 = lane & 15;

  __shared__ __align__(16) uint16_t Ks[64 * 64];      // [n][d] swizzled
  __shared__ __align__(16) uint16_t Vt[64 * 64];      // [d][n] swizzled
  __shared__ __align__(16) uint16_t Ps[4][32 * 72];   // per-wave P (2 frags)

  // Q fragments (B-operand layout: lane l16 = q-row), pre-scaled by 1/8
  const int qrow0 = qt2 * 128 + wave * 16 + l16;      // frag0
  const int qrow1 = qrow0 + 64;                       // frag1
  bf16x8 qf0[2], qf1[2];
#pragma unroll
  for (int s = 0; s < 2; s++) {
    union { bf16x8 v; uint16_t u[8]; } t0, t1;
    t0.v = *(const bf16x8*)(Q + ((size_t)(b * 2048 + qrow0) * 1024) + h * 64 + s * 32 + quad * 8);
    t1.v = *(const bf16x8*)(Q + ((size_t)(b * 2048 + qrow1) * 1024) + h * 64 + s * 32 + quad * 8);
#pragma unroll
    for (int j = 0; j < 8; j++) {
      t0.u[j] = f2bf(bf2f(t0.u[j]) * 0.125f);
      t1.u[j] = f2bf(bf2f(t1.u[j]) * 0.125f);
    }
    qf0[s] = t0.v;
    qf1[s] = t1.v;
  }

  const size_t vbase = ((size_t)((b * 16 + h) * 64)) * 2048;  // VT head base

  float lsum0 = 0.f, lsum1 = 0.f;
  f32x4 o0[4] = {}, o1[4] = {};

  const int nkt = 2 * qt2 + 2;
  for (int kt = 0; kt < nkt; kt++) {
    if (kt) __syncthreads();
#pragma unroll
    for (int i = 0; i < 2; i++) {
      const int c = i * 256 + tid;
      const int r = c >> 3, pc = ((c & 7) ^ (r & 7)) << 3;
      async_copy16(K + ((size_t)(b * 2048 + kt * 64 + r) * 1024) + h * 64 + pc,
                   Ks + (i * 256 + (tid & 192)) * 8);
      async_copy16(VT + vbase + (size_t)r * 2048 + kt * 64 + pc,
                   Vt + (i * 256 + (tid & 192)) * 8);
    }
    __syncthreads();

    const bool f0 = (kt < nkt - 1);  // low frag fully masked at last kt

    // ---- frag1 S^T ----
    {
      f32x4 sacc[4] = {};
#pragma unroll
      for (int s = 0; s < 2; s++)
#pragma unroll
        for (int t = 0; t < 4; t++) {
          const int R = t * 16 + l16;
          bf16x8 kf = *(const bf16x8*)(Ks + R * 64 + (((s * 4 + quad) ^ (R & 7)) << 3));
          sacc[t] = __builtin_amdgcn_mfma_f32_16x16x32_bf16(kf, qf1[s], sacc[t], 0, 0, 0);
        }
      if (kt == nkt - 1) {
#pragma unroll
        for (int t = 0; t < 4; t++)
#pragma unroll
          for (int r = 0; r < 4; r++)
            if (kt * 64 + t * 16 + quad * 4 + r > qrow1) sacc[t][r] = -1e30f;
      }
#pragma unroll
      for (int t = 0; t < 4; t++) {
        float p0 = __expf(sacc[t][0]), p1 = __expf(sacc[t][1]);
        float p2 = __expf(sacc[t][2]), p3 = __expf(sacc[t][3]);
        lsum1 += (p0 + p1) + (p2 + p3);
        uint2 pk;
        pk.x = (unsigned)f2bf(p0) | ((unsigned)f2bf(p1) << 16);
        pk.y = (unsigned)f2bf(p2) | ((unsigned)f2bf(p3) << 16);
        *(uint2*)(&Ps[wave][(16 + l16) * 72 + t * 16 + quad * 4]) = pk;
      }
    }
    // ---- frag0 S^T ----
    if (f0) {
      f32x4 sacc[4] = {};
#pragma unroll
      for (int s = 0; s < 2; s++)
#pragma unroll
        for (int t = 0; t < 4; t++) {
          const int R = t * 16 + l16;
          bf16x8 kf = *(const bf16x8*)(Ks + R * 64 + (((s * 4 + quad) ^ (R & 7)) << 3));
          sacc[t] = __builtin_amdgcn_mfma_f32_16x16x32_bf16(kf, qf0[s], sacc[t], 0, 0, 0);
        }
      if (kt == nkt - 2) {
#pragma unroll
        for (int t = 0; t < 4; t++)
#pragma unroll
          for (int r = 0; r < 4; r++)
            if (kt * 64 + t * 16 + quad * 4 + r > qrow0) sacc[t][r] = -1e30f;
      }
#pragma unroll
      for (int t = 0; t < 4; t++) {
        float p0 = __expf(sacc[t][0]), p1 = __expf(sacc[t][1]);
        float p2 = __expf(sacc[t][2]), p3 = __expf(sacc[t][3]);
        lsum0 += (p0 + p1) + (p2 + p3);
        uint2 pk;
        pk.x = (unsigned)f2bf(p0) | ((unsigned)f2bf(p1) << 16);
        pk.y = (unsigned)f2bf(p2) | ((unsigned)f2bf(p3) << 16);
        *(uint2*)(&Ps[wave][l16 * 72 + t * 16 + quad * 4]) = pk;
      }
    }
    // ---- PV ----
#pragma unroll
    for (int s = 0; s < 2; s++) {
      const bf16x8 pa1 = *(const bf16x8*)(&Ps[wave][(16 + l16) * 72 + s * 32 + quad * 8]);
#pragma unroll
      for (int t = 0; t < 4; t++) {
        const int R = t * 16 + l16;
        const bf16x8 vb = *(const bf16x8*)(Vt + R * 64 + (((s * 4 + quad) ^ (R & 7)) << 3));
        o1[t] = __builtin_amdgcn_mfma_f32_16x16x32_bf16(pa1, vb, o1[t], 0, 0, 0);
      }
    }
    if (f0) {
#pragma unroll
      for (int s = 0; s < 2; s++) {
        const bf16x8 pa0 = *(const bf16x8*)(&Ps[wave][l16 * 72 + s * 32 + quad * 8]);
#pragma unroll
        for (int t = 0; t < 4; t++) {
          const int R = t * 16 + l16;
          const bf16x8 vb = *(const bf16x8*)(Vt + R * 64 + (((s * 4 + quad) ^ (R & 7)) << 3));
          o0[t] = __builtin_amdgcn_mfma_f32_16x16x32_bf16(pa0, vb, o0[t], 0, 0, 0);
        }
      }
    }
  }
  // row-sum reduce over quads (q-row = l16); broadcast inverse to C/D rows
  lsum0 += __shfl_xor(lsum0, 16);
  lsum0 += __shfl_xor(lsum0, 32);
  lsum1 += __shfl_xor(lsum1, 16);
  lsum1 += __shfl_xor(lsum1, 32);
  const float inv0 = 1.f / lsum0, inv1 = 1.f / lsum1;
  float invr0[4], invr1[4];
#pragma unroll
  for (int r = 0; r < 4; r++) {
    invr0[r] = __shfl(inv0, quad * 4 + r);
    invr1[r] = __shfl(inv1, quad * 4 + r);
  }
#pragma unroll
  for (int t = 0; t < 4; t++)
#pragma unroll
    for (int r = 0; r < 4; r++) {
      const int qg0 = qt2 * 128 + wave * 16 + quad * 4 + r;
      AO[((size_t)(b * 2048 + qg0) * 1024) + h * 64 + t * 16 + l16] =
          f2bf(o0[t][r] * invr0[r]);
      AO[((size_t)(b * 2048 + qg0 + 64) * 1024) + h * 64 + t * 16 + l16] =
          f2bf(o1[t][r] * invr1[r]);
    }
}

extern "C" void kernel_launch(void* const* d_in, const int* in_sizes, int n_in,
                              void* d_out, int out_size, void* d_ws, size_t ws_size,
                              hipStream_t stream) {
  const float* query = (const float*)d_in[0];
  const float* key   = (const float*)d_in[1];
  const float* value = (const float*)d_in[2];
  const float* Wq = (const float*)d_in[3];
  const float* bq = (const float*)d_in[4];
  const float* Wk = (const float*)d_in[5];
  const float* bk = (const float*)d_in[6];
  const float* Wv = (const float*)d_in[7];
  const float* bv = (const float*)d_in[8];
  const float* Wo = (const float*)d_in[9];
  const float* bo = (const float*)d_in[10];
  float* out = (float*)d_out;

  uint16_t* ws = (uint16_t*)d_ws;
  uint16_t* Qb  = ws;                         // [0,8M) bytes: bf16 (roped)
  uint16_t* Kb  = ws + (size_t)4194304;       // [8M,16M) (roped)
  uint16_t* VTb = ws + (size_t)8388608;       // [16M,24M) V^T [b,h,d,s]
  uint16_t* AOb = ws + (size_t)12582912;      // [24M,32M)

  dim3 blk(256);

  if (ws_size >= (size_t)64 * 1024 * 1024) {
    // Fast path: bf16 copies of activations + all weights -> pure-DMA GEMMs.
    uint16_t* Qc  = ws + (size_t)16777216;    // [32M,40M) query bf16
    uint16_t* Kc  = ws + (size_t)20971520;    // [40M,48M) key bf16
    uint16_t* Vc  = ws + (size_t)25165824;    // [48M,56M) value bf16
    uint16_t* Wqc = ws + (size_t)29360128;    // [56M,58M)
    uint16_t* Wkc = ws + (size_t)30408704;    // [58M,60M)
    uint16_t* Wvc = ws + (size_t)31457280;    // [60M,62M)
    uint16_t* Woc = ws + (size_t)32505856;    // [62M,64M)

    cvt_kernel<<<dim3(512, 1, 4), blk, 0, stream>>>(
        Wq, Wqc, Wk, Wkc, Wv, Wvc, Wo, Woc);
    cvt_kernel<<<dim3(2048, 1, 3), blk, 0, stream>>>(
        query, Qc, key, Kc, value, Vc, nullptr, nullptr);
    // QKV: pure bf16, 128x128 tile, both operands global_load_lds,
    // 32KB LDS -> 5 blocks/CU; grid 8 n-tiles x 32 m-tiles x 3
    gemm3_kernel<false, false, false, true, true, 128, 4><<<dim3(8, 32, 3), blk, 0, stream>>>(
        Qc, Wqc, bq, Qb,
        Kc, Wkc, bk, Kb,
        Vc, Wvc, bv, VTb,
        4096, 1024, 1024);
    flash_kernel<<<dim3(512), blk, 0, stream>>>(Qb, Kb, VTb, AOb);
    // out-proj: pure bf16 128x64, both DMA, 24KB LDS -> 6 blocks/CU
    gemm3_kernel<false, false, true, false, false, 128, 2><<<dim3(16, 32, 1), blk, 0, stream>>>(
        AOb, Woc, bo, out,
        AOb, Woc, bo, out,
        AOb, Woc, bo, out,
        4096, 1024, 1024);
  } else {
    // Fallback: R0 GEMM configuration (32MB workspace).
    uint16_t* Wqc = AOb;
    uint16_t* Wkc = AOb + (size_t)1048576;
    uint16_t* Wvc = AOb + (size_t)2097152;
    cvt_kernel<<<dim3(512, 1, 3), blk, 0, stream>>>(
        Wq, Wqc, Wk, Wkc, Wv, Wvc, nullptr, nullptr);
    gemm3_kernel<true, false, false, true, true, 128, 2><<<dim3(16, 32, 3), blk, 0, stream>>>(
        query, Wqc, bq, Qb,
        key,   Wkc, bk, Kb,
        value, Wvc, bv, VTb,
        4096, 1024, 1024);
    flash_kernel<<<dim3(512), blk, 0, stream>>>(Qb, Kb, VTb, AOb);
    gemm3_kernel<false, true, true, false, false, 128, 2><<<dim3(16, 32, 1), blk, 0, stream>>>(
        AOb, Wo, bo, out,
        AOb, Wo, bo, out,
        AOb, Wo, bo, out,
        4096, 1024, 1024);
  }
}